// Round 6
// baseline (123.130 us; speedup 1.0000x reference)
//
#include <hip/hip_runtime.h>
#include <hip/hip_fp16.h>

#define KNB 31
#define CH 64
#define TEMP_INV 10.0f   // 1 / temperature(0.1)

typedef _Float16 h2 __attribute__((ext_vector_type(2)));
typedef float f2 __attribute__((ext_vector_type(2)));

#if (__has_builtin(__builtin_amdgcn_cvt_pk_fp8_f32) && __has_builtin(__builtin_amdgcn_cvt_pk_f32_fp8))
#define HAS_FP8 1
#else
#define HAS_FP8 0
#endif

// ---------------------------------------------------------------------------
// ws layout:
//   bytes [0, 16)    : double ws[2]  (sum(loss*mask), sum(mask))
//   bytes [16, 20)   : unsigned done-counter (last-block finalize)
//   bytes [256, ...) : quantized feature table (fp8: N*64 B, fp16: N*128 B)
// ---------------------------------------------------------------------------

__device__ __forceinline__ float dot2acc(h2 d, float s) {
#if defined(__has_builtin) && __has_builtin(__builtin_amdgcn_fdot2)
    return __builtin_amdgcn_fdot2(d, d, s, false);
#else
    const float x = (float)d[0], y = (float)d[1];
    return s + x * x + y * y;
#endif
}

__global__ void ch_init_ws(double* __restrict__ ws, unsigned* __restrict__ ctr) {
    ws[0] = 0.0;
    ws[1] = 0.0;
    *ctr  = 0u;
}

#if HAS_FP8
// features f32 -> fp8 e4m3 table (8 floats -> 8 bytes per thread); zero ws.
__global__ __launch_bounds__(256) void ch_cvt8(
    const float* __restrict__ in, unsigned char* __restrict__ out,
    double* __restrict__ ws, unsigned* __restrict__ ctr, int total8)
{
    const int idx = blockIdx.x * blockDim.x + threadIdx.x;
    if (idx == 0) { ws[0] = 0.0; ws[1] = 0.0; *ctr = 0u; }
    if (idx >= total8) return;
    const float4* ip = reinterpret_cast<const float4*>(in) + (size_t)idx * 2;
    const float4 a = ip[0];
    const float4 b = ip[1];
    unsigned lo = 0u, hi = 0u;
    lo = __builtin_amdgcn_cvt_pk_fp8_f32(a.x, a.y, lo, false);
    lo = __builtin_amdgcn_cvt_pk_fp8_f32(a.z, a.w, lo, true);
    hi = __builtin_amdgcn_cvt_pk_fp8_f32(b.x, b.y, hi, false);
    hi = __builtin_amdgcn_cvt_pk_fp8_f32(b.z, b.w, hi, true);
    uint2 o; o.x = lo; o.y = hi;
    reinterpret_cast<uint2*>(out)[idx] = o;
}
#endif

// features f32 -> fp16 table (8 floats/thread); zero ws. (fallback path)
__global__ __launch_bounds__(256) void ch_cvt16(
    const float* __restrict__ in, __half* __restrict__ out,
    double* __restrict__ ws, unsigned* __restrict__ ctr, int total8)
{
    const int idx = blockIdx.x * blockDim.x + threadIdx.x;
    if (idx == 0) { ws[0] = 0.0; ws[1] = 0.0; *ctr = 0u; }
    if (idx >= total8) return;
    const float4* ip = reinterpret_cast<const float4*>(in) + (size_t)idx * 2;
    const float4 a = ip[0];
    const float4 b = ip[1];
    union { uint4 u; __half2 h[4]; } o;
    o.h[0] = __floats2half2_rn(a.x, a.y);
    o.h[1] = __floats2half2_rn(a.z, a.w);
    o.h[2] = __floats2half2_rn(b.x, b.y);
    o.h[3] = __floats2half2_rn(b.z, b.w);
    reinterpret_cast<uint4*>(out)[idx] = o.u;
}

// ---------------------------------------------------------------------------
// Main: R2-proven structure. 4 lanes/point, lane sub owns 16 channels,
// quad-cooperative row gathers, online softmax. MODE: 0=fp8, 1=fp16, 2=f32.
// Last block finalizes out[0] (threadfence + counter; atomic reads for
// cross-XCD coherence).
// ---------------------------------------------------------------------------
template <int MODE>
__global__ __launch_bounds__(256) void ch_main_o(
    const unsigned char* __restrict__ tab8,   // MODE 0
    const __half*        __restrict__ tab16,  // MODE 1
    const float*         __restrict__ feat,   // MODE 2
    const int*           __restrict__ labels,
    const int*           __restrict__ nidx,
    double*              __restrict__ ws,
    unsigned*            __restrict__ ctr,
    float*               __restrict__ out,
    int n)
{
    const int t   = threadIdx.x;
    const int i   = blockIdx.x * (256 / 4) + (t >> 2);
    const int sub = t & 3;

    float loss_w = 0.0f;
    float pm_f   = 0.0f;

    if (i < n) {
        // ---- own 16 channels ------------------------------------------------
        float fA[16];                              // MODE 0/2
        union { uint4 u[2]; h2 h[8]; } A16;        // MODE 1
        if constexpr (MODE == 0) {
            union { uint4 u; unsigned w[4]; } Au;
            Au.u = *(reinterpret_cast<const uint4*>(tab8 + (size_t)i * CH) + sub);
            #pragma unroll
            for (int q = 0; q < 4; ++q) {
                const f2 p0 = __builtin_amdgcn_cvt_pk_f32_fp8(Au.w[q], false);
                const f2 p1 = __builtin_amdgcn_cvt_pk_f32_fp8(Au.w[q], true);
                fA[4 * q + 0] = p0[0]; fA[4 * q + 1] = p0[1];
                fA[4 * q + 2] = p1[0]; fA[4 * q + 3] = p1[1];
            }
        } else if constexpr (MODE == 1) {
            const uint4* ap = reinterpret_cast<const uint4*>(tab16 + (size_t)i * CH + sub * 16);
            A16.u[0] = ap[0];
            A16.u[1] = ap[1];
        } else {
            const float4* ap = reinterpret_cast<const float4*>(feat + (size_t)i * CH + sub * 16);
            #pragma unroll
            for (int q = 0; q < 4; ++q) {
                const float4 v = ap[q];
                fA[4 * q] = v.x; fA[4 * q + 1] = v.y; fA[4 * q + 2] = v.z; fA[4 * q + 3] = v.w;
            }
        }

        const int lab = labels[i];

        float m  = -1e30f;  // running max logit
        float se = 0.0f;
        float sp = 0.0f;
        int   cnt = 0;

        #pragma unroll 2
        for (int j = 0; j < KNB; ++j) {
            const int nj = nidx[(size_t)i * KNB + j];   // quad-broadcast

            float s = 0.0f;
            if constexpr (MODE == 0) {
                union { uint4 u; unsigned w[4]; } Bu;
                Bu.u = *(reinterpret_cast<const uint4*>(tab8 + (size_t)nj * CH) + sub);
                #pragma unroll
                for (int q = 0; q < 4; ++q) {
                    const f2 p0 = __builtin_amdgcn_cvt_pk_f32_fp8(Bu.w[q], false);
                    const f2 p1 = __builtin_amdgcn_cvt_pk_f32_fp8(Bu.w[q], true);
                    float d;
                    d = fA[4 * q + 0] - p0[0]; s = fmaf(d, d, s);
                    d = fA[4 * q + 1] - p0[1]; s = fmaf(d, d, s);
                    d = fA[4 * q + 2] - p1[0]; s = fmaf(d, d, s);
                    d = fA[4 * q + 3] - p1[1]; s = fmaf(d, d, s);
                }
            } else if constexpr (MODE == 1) {
                union { uint4 u[2]; h2 h[8]; } B;
                const uint4* bp = reinterpret_cast<const uint4*>(tab16 + (size_t)nj * CH + sub * 16);
                B.u[0] = bp[0];
                B.u[1] = bp[1];
                #pragma unroll
                for (int q = 0; q < 8; ++q) {
                    const h2 d = A16.h[q] - B.h[q];
                    s = dot2acc(d, s);
                }
            } else {
                const float4* bp = reinterpret_cast<const float4*>(feat + (size_t)nj * CH + sub * 16);
                #pragma unroll
                for (int q = 0; q < 4; ++q) {
                    const float4 v = bp[q];
                    float d;
                    d = fA[4 * q]     - v.x; s = fmaf(d, d, s);
                    d = fA[4 * q + 1] - v.y; s = fmaf(d, d, s);
                    d = fA[4 * q + 2] - v.z; s = fmaf(d, d, s);
                    d = fA[4 * q + 3] - v.w; s = fmaf(d, d, s);
                }
            }
            s += __shfl_xor(s, 1);
            s += __shfl_xor(s, 2);

            const float l = -(sqrtf(s) + 1e-8f);
            const bool pm = (labels[nj] == lab);         // quad-broadcast
            cnt += pm ? 1 : 0;

            if (l > m) {
                const float r = __expf((m - l) * TEMP_INV);
                se *= r;
                sp *= r;
                m = l;
            }
            const float e = __expf((l - m) * TEMP_INV);
            se += e;
            if (pm) sp += e;
        }

        if (sub == 0 && cnt > 0 && cnt < KNB) {
            loss_w = -logf(sp / se + 1e-8f);
            pm_f   = 1.0f;
        }
    }

    // ---- block reduction, one double atomic per block -----------------------
    __shared__ float s_l[256];
    __shared__ float s_c[256];
    s_l[t] = loss_w;
    s_c[t] = pm_f;
    __syncthreads();
    #pragma unroll
    for (int off = 128; off > 0; off >>= 1) {
        if (t < off) {
            s_l[t] += s_l[t + off];
            s_c[t] += s_c[t + off];
        }
        __syncthreads();
    }
    if (t == 0) {
        atomicAdd(ws,     (double)s_l[0]);
        atomicAdd(ws + 1, (double)s_c[0]);
        __threadfence();
        const unsigned old = atomicAdd(ctr, 1u);
        if (old == gridDim.x - 1) {
            // all blocks' data atomics are globally visible (fence+counter);
            // read via atomic RMW for cross-XCD coherence.
            const double sl = atomicAdd(ws, 0.0);
            const double sc = atomicAdd(ws + 1, 0.0);
            const double c  = (sc < 1.0) ? 1.0 : sc;
            out[0] = (float)(sl / c);   // WEIGHT = 1.0
        }
    }
}

extern "C" void kernel_launch(void* const* d_in, const int* in_sizes, int n_in,
                              void* d_out, int out_size, void* d_ws, size_t ws_size,
                              hipStream_t stream) {
    const float* feat   = (const float*)d_in[0];
    const int*   labels = (const int*)d_in[1];
    const int*   nidx   = (const int*)d_in[2];
    float*       out    = (float*)d_out;
    double*      ws     = (double*)d_ws;
    unsigned*    ctr    = (unsigned*)((char*)d_ws + 16);

    const int n = in_sizes[1];                 // N = 100000
    const int total8 = n * CH / 8;
    const int blocks = (n + 63) / 64;          // 64 points per 256-thread block

#if HAS_FP8
    if (ws_size >= 256 + (size_t)n * CH) {     // fp8 table: N*64 B
        unsigned char* tab = (unsigned char*)d_ws + 256;
        ch_cvt8<<<(total8 + 255) / 256, 256, 0, stream>>>(feat, tab, ws, ctr, total8);
        ch_main_o<0><<<blocks, 256, 0, stream>>>(tab, nullptr, nullptr,
                                                 labels, nidx, ws, ctr, out, n);
        return;
    }
#endif
    if (ws_size >= 256 + (size_t)n * CH * 2) { // fp16 table: N*128 B
        __half* tab = reinterpret_cast<__half*>((char*)d_ws + 256);
        ch_cvt16<<<(total8 + 255) / 256, 256, 0, stream>>>(feat, tab, ws, ctr, total8);
        ch_main_o<1><<<blocks, 256, 0, stream>>>(nullptr, tab, nullptr,
                                                 labels, nidx, ws, ctr, out, n);
    } else {                                   // f32 direct
        ch_init_ws<<<1, 1, 0, stream>>>(ws, ctr);
        ch_main_o<2><<<blocks, 256, 0, stream>>>(nullptr, nullptr, feat,
                                                 labels, nidx, ws, ctr, out, n);
    }
}